// Round 1
// 273.714 us; speedup vs baseline: 1.0846x; 1.0846x over previous
//
#include <hip/hip_runtime.h>
#include <math.h>

namespace {

constexpr int N_PTS  = 1000000;
constexpr int C_CLS  = 20;
constexpr int N_B    = 4;
constexpr int L_LAB  = 200;
constexpr int LW     = L_LAB + 1;   // 201
constexpr int N_INST = 64;
constexpr int M_PTS  = 300000;
constexpr int T_PROP = 320000;
constexpr int IGN    = -100;
constexpr int PREP   = 128;

// ---- workspace layout (bytes) ----
constexpr size_t OFF_G      = 0;       // 5 doubles (reserve 64B)
constexpr size_t OFF_INTER  = 64;      // 64 doubles each
constexpr size_t OFF_UP     = 576;
constexpr size_t OFF_UG     = 1088;
constexpr size_t OFF_WBS    = 1600;
constexpr size_t OFF_SN     = 2112;
constexpr size_t OFF_HFULL  = 2624;    // 804 ints
constexpr size_t OFF_HMASK  = 5840;    // 804 ints
constexpr size_t OFF_IHIST  = 9056;    // 64*201 ints = 51456 B
constexpr size_t OFF_FLAGS  = 60512;   // 64 ints
constexpr size_t ZERO_BYTES = 60768;
constexpr size_t OFF_META   = 60800;   // 300000 ushorts
constexpr size_t WS_REQUIRED = OFF_META + (size_t)M_PTS * 2;

__device__ __forceinline__ float waveSumF(float v) {
  #pragma unroll
  for (int off = 32; off > 0; off >>= 1) v += __shfl_down(v, off, 64);
  return v;
}
__device__ __forceinline__ int waveMaxI(int v) {
  #pragma unroll
  for (int off = 32; off > 0; off >>= 1) v = max(v, __shfl_down(v, off, 64));
  return v;
}

// ---------------------------------------------------------------------------
// K_A: one dispatch, four independent jobs split by blockIdx.x.
//   [0, 1024)        : per-point losses — wave-cooperative LDS staging so every
//                      global load is lane-consecutive float4 (coalesced).
//   [1024, 1280)     : hist_full[B][LW] over N points (int4 scan, LDS hist)
//   [1280, 1536)     : proposal histogram -> inst_hist[64][LW] (global atomics)
//   [1536, 1792)     : hist_mask[B][LW] over M points + meta16 (batched gathers)
// ---------------------------------------------------------------------------
constexpr int PB_PT   = 1024;
constexpr int PB_HF   = 256;
constexpr int PB_PROP = 256;
constexpr int PB_HM   = 256;
constexpr int A_BLOCKS = PB_PT + PB_HF + PB_PROP + PB_HM;

__global__ __launch_bounds__(256) void k_A(const float* __restrict__ scores,
                                           const float* __restrict__ pt_off,
                                           const float* __restrict__ info,
                                           const float* __restrict__ coords,
                                           const int* __restrict__ sem_lab,
                                           const int* __restrict__ inst_lab,
                                           const int* __restrict__ obj_idx,
                                           const int* __restrict__ batch_ids,
                                           const int* __restrict__ prop_idx,
                                           const int* __restrict__ prop_off,
                                           const int* __restrict__ batch_off,
                                           double* __restrict__ g,
                                           int* __restrict__ hist_full,
                                           int* __restrict__ hist_mask,
                                           int* __restrict__ inst_hist,
                                           unsigned short* __restrict__ meta,
                                           int write_meta) {
  // 20480 B: 4 waves x 320 float4 (5120 B/wave). Other branches alias the
  // front of this as int[] (max 804 ints = 3216 B).
  __shared__ float4 shbuf4[4 * 320];
  int*   sh  = reinterpret_cast<int*>(shbuf4);
  float* shf = reinterpret_cast<float*>(shbuf4);
  const int bx = blockIdx.x;

  if (bx < PB_PT) {
    // ================= per-point losses (wave tile = 64 points) =============
    const int lane = threadIdx.x & 63, wv = threadIdx.x >> 6;
    float4* shw4 = shbuf4 + wv * 320;
    float*  shwf = reinterpret_cast<float*>(shw4);
    float s_nll = 0.f, s_cnt = 0.f, s_dist = 0.f, s_dir = 0.f, s_val = 0.f;

    constexpr int NT      = N_PTS / 64;   // 15625 tiles, exact
    constexpr int TSTRIDE = PB_PT * 4;    // 4096 waves total
    const int base = bx * 4 + wv;
    // block-uniform trip count (wave 0 has the smallest base => most iters)
    const int nit = (NT - bx * 4 + TSTRIDE - 1) / TSTRIDE;

    for (int it = 0; it < nit; ++it) {
      const int tile = base + it * TSTRIDE;
      const bool act = tile < NT;          // wave-uniform
      int sl = 0, il = IGN;

      // ---- phase 1: stage scores (320 f4, lane-consecutive) + labels ----
      if (act) {
        const int p = tile * 64 + lane;
        sl = sem_lab[p];
        il = inst_lab[p];
        const float4* s4 = reinterpret_cast<const float4*>(scores) + (size_t)tile * 320;
        #pragma unroll
        for (int r = 0; r < 5; ++r) shw4[r * 64 + lane] = s4[r * 64 + lane];
      }
      __syncthreads();

      // ---- softmax NLL from LDS (row = 80 B at lane*80, conflict-free) ----
      if (act) {
        float mx = -3.4e38f;
        #pragma unroll
        for (int r = 0; r < 5; ++r) {
          const float4 a = shw4[lane * 5 + r];
          mx = fmaxf(mx, fmaxf(fmaxf(a.x, a.y), fmaxf(a.z, a.w)));
        }
        float se = 0.f;
        #pragma unroll
        for (int r = 0; r < 5; ++r) {
          const float4 a = shw4[lane * 5 + r];
          se += __expf(a.x - mx) + __expf(a.y - mx) + __expf(a.z - mx) + __expf(a.w - mx);
        }
        const float xs = shwf[lane * 20 + ((sl == IGN) ? 0 : sl)];
        if (sl != IGN) { s_nll += (mx + __logf(se)) - xs; s_cnt += 1.f; }
      }
      __syncthreads();

      // ---- phase 2: stage coords(48 f4) + off(48 f4) + info(144 f4) ----
      if (act) {
        const float4* c4 = reinterpret_cast<const float4*>(coords) + (size_t)tile * 48;
        const float4* o4 = reinterpret_cast<const float4*>(pt_off) + (size_t)tile * 48;
        const float4* i4 = reinterpret_cast<const float4*>(info)   + (size_t)tile * 144;
        if (lane < 48) { shw4[lane] = c4[lane]; shw4[48 + lane] = o4[lane]; }
        shw4[96 + lane]  = i4[lane];
        shw4[160 + lane] = i4[64 + lane];
        if (lane < 16) shw4[224 + lane] = i4[128 + lane];
      }
      __syncthreads();

      // ---- geometry losses from LDS (stride 3 / 9 dwords: conflict-free) ----
      if (act && il != IGN) {
        const float cx = shwf[3 * lane + 0], cy = shwf[3 * lane + 1], cz = shwf[3 * lane + 2];
        const float ox = shwf[192 + 3 * lane + 0], oy = shwf[192 + 3 * lane + 1], oz = shwf[192 + 3 * lane + 2];
        const float gx = shwf[384 + 9 * lane + 0] - cx;
        const float gy = shwf[384 + 9 * lane + 1] - cy;
        const float gz = shwf[384 + 9 * lane + 2] - cz;
        s_val  += 1.f;
        s_dist += fabsf(ox - gx) + fabsf(oy - gy) + fabsf(oz - gz);
        const float gn = sqrtf(gx * gx + gy * gy + gz * gz) + 1e-8f;
        const float pn = sqrtf(ox * ox + oy * oy + oz * oz) + 1e-8f;
        s_dir += -((gx * ox + gy * oy + gz * oz) / (gn * pn));
      }
      __syncthreads();
    }

    // ---- block reduction ----
    float vals[5] = { s_nll, s_cnt, s_dist, s_dir, s_val };
    #pragma unroll
    for (int k = 0; k < 5; ++k) {
      const float t = waveSumF(vals[k]);
      if (lane == 0) shf[k * 4 + wv] = t;
    }
    __syncthreads();
    if (threadIdx.x < 5) {
      const float s = shf[threadIdx.x * 4 + 0] + shf[threadIdx.x * 4 + 1] +
                      shf[threadIdx.x * 4 + 2] + shf[threadIdx.x * 4 + 3];
      atomicAdd(&g[threadIdx.x], (double)s);
    }
  } else if (bx < PB_PT + PB_HF) {
    // ================= hist_full over N points =================
    for (int t = threadIdx.x; t < N_B * LW; t += blockDim.x) sh[t] = 0;
    __syncthreads();
    const int b1 = batch_off[1], b2 = batch_off[2], b3 = batch_off[3];
    const int blk = bx - PB_PT;
    const int4* il4p = reinterpret_cast<const int4*>(inst_lab);
    const int nq = N_PTS / 4;
    for (int q = blk * blockDim.x + threadIdx.x; q < nq; q += PB_HF * blockDim.x) {
      const int4 v = il4p[q];
      const int p = q * 4;
      const int ils[4] = { v.x, v.y, v.z, v.w };
      #pragma unroll
      for (int k = 0; k < 4; ++k) {
        const int lab = (ils[k] == IGN) ? 0 : (ils[k] + 1);
        const int pp = p + k;
        int pb = 0;
        if (pp >= b1) pb = 1;
        if (pp >= b2) pb = 2;
        if (pp >= b3) pb = 3;
        atomicAdd(&sh[pb * LW + lab], 1);
      }
    }
    __syncthreads();
    for (int t = threadIdx.x; t < N_B * LW; t += blockDim.x)
      if (sh[t]) atomicAdd(&hist_full[t], sh[t]);
  } else if (bx < PB_PT + PB_HF + PB_PROP) {
    // ================= proposal histogram -> inst_hist (global atomics) ======
    if (threadIdx.x <= N_INST) sh[threadIdx.x] = prop_off[threadIdx.x];  // 65 ints
    __syncthreads();
    const int blk = bx - PB_PT - PB_HF;
    const int4* pi4 = reinterpret_cast<const int4*>(prop_idx);  // 2 proposals per int4
    const int nq = T_PROP / 2;   // index in int4 units over (T,2) int pairs
    for (int q = blk * blockDim.x + threadIdx.x; q < nq; q += PB_PROP * blockDim.x) {
      const int4 v = pi4[q];     // proposals 2q (y) and 2q+1 (w)
      const int t0 = 2 * q, t1 = 2 * q + 1;
      const int il0 = inst_lab[v.y];
      const int il1 = inst_lab[v.w];
      // binary search: first idx with prop_off > t  (prop_off[0]=0, [64]=T)
      int lo0 = 0, hi0 = N_INST + 1, lo1 = 0, hi1 = N_INST + 1;
      #pragma unroll
      for (int s = 0; s < 7; ++s) {
        const int m0 = (lo0 + hi0) >> 1;
        if (m0 <= N_INST && sh[m0] <= t0) lo0 = m0 + 1; else hi0 = m0;
        const int m1 = (lo1 + hi1) >> 1;
        if (m1 <= N_INST && sh[m1] <= t1) lo1 = m1 + 1; else hi1 = m1;
      }
      const int seg0 = min(lo0 - 1, N_INST - 1);
      const int seg1 = min(lo1 - 1, N_INST - 1);
      const int lab0 = (il0 == IGN) ? 0 : (il0 + 1);
      const int lab1 = (il1 == IGN) ? 0 : (il1 + 1);
      atomicAdd(&inst_hist[seg0 * LW + lab0], 1);
      atomicAdd(&inst_hist[seg1 * LW + lab1], 1);
    }
  } else {
    // ================= hist_mask over M points + meta =================
    for (int t = threadIdx.x; t < N_B * LW; t += blockDim.x) sh[t] = 0;
    __syncthreads();
    const int blk = bx - PB_PT - PB_HF - PB_PROP;
    const int4* oi4 = reinterpret_cast<const int4*>(obj_idx);
    const int4* bi4 = reinterpret_cast<const int4*>(batch_ids);
    ushort4* m4 = reinterpret_cast<ushort4*>(meta);
    const int nq = M_PTS / 4;
    for (int q = blk * blockDim.x + threadIdx.x; q < nq; q += PB_HM * blockDim.x) {
      const int4 o = oi4[q];
      const int4 b = bi4[q];
      // 8 independent gathers issued before any use
      const int il0 = inst_lab[o.x], il1 = inst_lab[o.y],
                il2 = inst_lab[o.z], il3 = inst_lab[o.w];
      const int sm0 = sem_lab[o.x], sm1 = sem_lab[o.y],
                sm2 = sem_lab[o.z], sm3 = sem_lab[o.w];
      const int ml0 = (il0 == IGN) ? 0 : (il0 + 1);
      const int ml1 = (il1 == IGN) ? 0 : (il1 + 1);
      const int ml2 = (il2 == IGN) ? 0 : (il2 + 1);
      const int ml3 = (il3 == IGN) ? 0 : (il3 + 1);
      atomicAdd(&sh[b.x * LW + ml0], 1);
      atomicAdd(&sh[b.y * LW + ml1], 1);
      atomicAdd(&sh[b.z * LW + ml2], 1);
      atomicAdd(&sh[b.w * LW + ml3], 1);
      if (write_meta) {
        ushort4 mm;
        mm.x = (unsigned short)(ml0 | (sm0 << 8) | (b.x << 13));
        mm.y = (unsigned short)(ml1 | (sm1 << 8) | (b.y << 13));
        mm.z = (unsigned short)(ml2 | (sm2 << 8) | (b.z << 13));
        mm.w = (unsigned short)(ml3 | (sm3 << 8) | (b.w << 13));
        m4[q] = mm;
      }
    }
    __syncthreads();
    for (int t = threadIdx.x; t < N_B * LW; t += blockDim.x)
      if (sh[t]) atomicAdd(&hist_mask[t], sh[t]);
  }
}

// ---------------------------------------------------------------------------
// K_ARGMAX: per-instance mode (first-index ties) + packed flags
//   flags: {mode[0:8], skip[8], pos[9], batch[10:12], seg[12:17]}
// ---------------------------------------------------------------------------
__global__ __launch_bounds__(256) void k_argmax(const int* __restrict__ inst_hist,
                                                const int* __restrict__ hist_full,
                                                const int* __restrict__ hist_mask,
                                                const int* __restrict__ inst_batch_ids,
                                                const int* __restrict__ inst_seg,
                                                int* __restrict__ flags) {
  __shared__ int red[4];
  const int i = blockIdx.x;
  const int t = threadIdx.x;
  int key = 0;   // (cnt << 8) | (255 - bin): max -> largest cnt, then smallest bin
  if (t < LW) {
    const int cnt = inst_hist[i * LW + t];
    key = (cnt << 8) | (255 - t);
  }
  key = waveMaxI(key);
  const int lane = t & 63, wv = t >> 6;
  if (lane == 0) red[wv] = key;
  __syncthreads();
  if (t == 0) {
    int k = max(max(red[0], red[1]), max(red[2], red[3]));
    const int m = 255 - (k & 0xFF);
    const int b = inst_batch_ids[i];
    const int seg = inst_seg[i];
    const bool skip = (m == 0) || (seg <= 3);
    const float num = (float)hist_mask[b * LW + m];
    const float den = (float)hist_full[b * LW + m];
    const float cover = (den > 0.f) ? (num / den) : 0.f;
    const bool pos = (!skip) && (cover > 0.3f);
    flags[i] = m | (skip ? 0x100 : 0) | (pos ? 0x200 : 0) | (b << 10) | (seg << 12);
  }
}

// ---------------------------------------------------------------------------
// K_MASK: branchless float4 streaming of logits, per-instance partials.
// ---------------------------------------------------------------------------
template <bool USE_META>
__global__ __launch_bounds__(256) void k_mask(const float* __restrict__ logits,
                                              const unsigned short* __restrict__ meta,
                                              const int* __restrict__ obj_idx,
                                              const int* __restrict__ inst_lab,
                                              const int* __restrict__ sem_lab,
                                              const int* __restrict__ batch_ids,
                                              const int* __restrict__ flags,
                                              double* __restrict__ i_inter,
                                              double* __restrict__ i_up,
                                              double* __restrict__ i_ug,
                                              double* __restrict__ i_wbs,
                                              double* __restrict__ i_sn) {
  const int i  = blockIdx.y;
  const int fl = flags[i];
  const int  mode_i = fl & 0xFF;
  const bool skip   = (fl >> 8) & 1;
  const bool pos    = (fl >> 9) & 1;
  const int  bi     = (fl >> 10) & 3;
  const int  seg    = (fl >> 12) & 31;

  float inter = 0.f, up = 0.f, ug = 0.f, wbs = 0.f, sn = 0.f;

  if (USE_META) {
    const float4* row4 = reinterpret_cast<const float4*>(logits + (size_t)i * M_PTS);
    const ushort4* m4  = reinterpret_cast<const ushort4*>(meta);
    const int nq = M_PTS / 4;
    for (int q = blockIdx.x * blockDim.x + threadIdx.x; q < nq; q += gridDim.x * blockDim.x) {
      const float4  x4 = row4[q];
      const ushort4 d4 = m4[q];
      const float xs[4] = { x4.x, x4.y, x4.z, x4.w };
      const int   ds[4] = { d4.x, d4.y, d4.z, d4.w };
      #pragma unroll
      for (int k = 0; k < 4; ++k) {
        const int md = ds[k];
        const int ml = md & 0xFF;
        const int sm = (md >> 8) & 31;
        const int b  = (md >> 13) & 3;
        const bool w  = (b == bi) && (skip || (sm == seg));
        const bool gt = pos && (ml == mode_i);
        const float x  = xs[k];
        const float e  = __expf(-fabsf(x));
        const float r  = __builtin_amdgcn_rcpf(1.f + e);
        const float pr = (x >= 0.f) ? r : e * r;            // sigmoid
        const float sp = fmaxf(x, 0.f) + __logf(1.f + e);   // softplus
        const float wf = w ? 1.f : 0.f;
        const float gf = gt ? 1.f : 0.f;
        up    += wf * pr * pr;
        wbs   += wf;
        sn    += wf * (sp - gf * x);
        inter += wf * gf * pr;
        ug    += wf * gf;
      }
    }
  } else {
    const float* row = logits + (size_t)i * M_PTS;
    for (int j = blockIdx.x * blockDim.x + threadIdx.x; j < M_PTS; j += gridDim.x * blockDim.x) {
      const int o  = obj_idx[j];
      const int il = inst_lab[o];
      const int ml = (il == IGN) ? 0 : (il + 1);
      const int sm = sem_lab[o];
      const int b  = batch_ids[j];
      const bool w  = (b == bi) && (skip || (sm == seg));
      const bool gt = pos && (ml == mode_i);
      const float x  = row[j];
      const float e  = __expf(-fabsf(x));
      const float r  = __builtin_amdgcn_rcpf(1.f + e);
      const float pr = (x >= 0.f) ? r : e * r;
      const float sp = fmaxf(x, 0.f) + __logf(1.f + e);
      const float wf = w ? 1.f : 0.f;
      const float gf = gt ? 1.f : 0.f;
      up    += wf * pr * pr;
      wbs   += wf;
      sn    += wf * (sp - gf * x);
      inter += wf * gf * pr;
      ug    += wf * gf;
    }
  }

  __shared__ float red[5][4];
  float vals[5] = { inter, up, ug, wbs, sn };
  const int lane = threadIdx.x & 63, wv = threadIdx.x >> 6;
  #pragma unroll
  for (int k = 0; k < 5; ++k) {
    const float t = waveSumF(vals[k]);
    if (lane == 0) red[k][wv] = t;
  }
  __syncthreads();
  if (threadIdx.x < 5) {
    const float s = red[threadIdx.x][0] + red[threadIdx.x][1] + red[threadIdx.x][2] + red[threadIdx.x][3];
    double* dst = (threadIdx.x == 0) ? (i_inter + i)
                : (threadIdx.x == 1) ? (i_up + i)
                : (threadIdx.x == 2) ? (i_ug + i)
                : (threadIdx.x == 3) ? (i_wbs + i)
                                     : (i_sn + i);
    atomicAdd(dst, (double)s);
  }
}

// ---------------------------------------------------------------------------
// K_FINAL: 64 lanes, one instance each, shuffle-reduced (was serial 1-thread).
// ---------------------------------------------------------------------------
__global__ __launch_bounds__(64) void k_final(const double* __restrict__ g,
                                              const double* __restrict__ i_inter,
                                              const double* __restrict__ i_up,
                                              const double* __restrict__ i_ug,
                                              const double* __restrict__ i_wbs,
                                              const double* __restrict__ i_sn,
                                              const int* __restrict__ flags,
                                              const int* __restrict__ epoch,
                                              float* __restrict__ out) {
  const int i = threadIdx.x;           // 64 threads = 1 wave
  const bool act = epoch[0] > PREP;
  double sn = 0.0, wsum = 0.0, dice = 0.0, dcnt = 0.0;
  if (act) {
    wsum = i_wbs[i];
    sn   = i_sn[i];
    const bool skip = (flags[i] >> 8) & 1;
    if (!skip && wsum > 0.0) {
      const double un = i_up[i] + i_ug[i] + 1e-5;
      dice = 1.0 - 2.0 * i_inter[i] / un;
      dcnt = 1.0;
    }
    #pragma unroll
    for (int off = 32; off > 0; off >>= 1) {
      wsum += __shfl_down(wsum, off, 64);
      sn   += __shfl_down(sn,   off, 64);
      dice += __shfl_down(dice, off, 64);
      dcnt += __shfl_down(dcnt, off, 64);
    }
  }
  if (i == 0) {
    double loss = g[0] / fmax(g[1], 1.0);            // semantic
    const double vsum = g[4] + 1e-6;
    loss += g[2] / vsum + g[3] / vsum;               // offset norm + dir
    if (act) loss += sn / (wsum + 1e-6) + dice / (dcnt + 1e-6);
    out[0] = (float)loss;
  }
}

} // anonymous namespace

extern "C" void kernel_launch(void* const* d_in, const int* in_sizes, int n_in,
                              void* d_out, int out_size, void* d_ws, size_t ws_size,
                              hipStream_t stream) {
  const float* semantic_scores  = (const float*)d_in[0];
  const float* pt_offsets       = (const float*)d_in[1];
  const float* instance_info    = (const float*)d_in[2];
  const float* coords           = (const float*)d_in[3];
  const float* mask_logits      = (const float*)d_in[4];
  const int*   semantic_labels  = (const int*)d_in[5];
  const int*   instance_labels  = (const int*)d_in[6];
  const int*   object_idxs      = (const int*)d_in[7];
  const int*   proposals_idx    = (const int*)d_in[8];
  const int*   proposals_off    = (const int*)d_in[9];
  const int*   inst_batch_ids   = (const int*)d_in[10];
  const int*   batch_ids        = (const int*)d_in[11];
  const int*   batch_offsets    = (const int*)d_in[12];
  const int*   inst_seg         = (const int*)d_in[13];
  const int*   epoch            = (const int*)d_in[14];
  float* out = (float*)d_out;

  char* w = (char*)d_ws;
  double* g        = (double*)(w + OFF_G);
  double* i_inter  = (double*)(w + OFF_INTER);
  double* i_up     = (double*)(w + OFF_UP);
  double* i_ug     = (double*)(w + OFF_UG);
  double* i_wbs    = (double*)(w + OFF_WBS);
  double* i_sn     = (double*)(w + OFF_SN);
  int* hist_full   = (int*)(w + OFF_HFULL);
  int* hist_mask   = (int*)(w + OFF_HMASK);
  int* inst_hist   = (int*)(w + OFF_IHIST);
  int* flags       = (int*)(w + OFF_FLAGS);
  unsigned short* meta = (unsigned short*)(w + OFF_META);

  const bool use_meta = (ws_size >= WS_REQUIRED);

  (void)hipMemsetAsync(d_ws, 0, ZERO_BYTES, stream);

  k_A<<<A_BLOCKS, 256, 0, stream>>>(semantic_scores, pt_offsets, instance_info, coords,
                                    semantic_labels, instance_labels, object_idxs,
                                    batch_ids, proposals_idx, proposals_off, batch_offsets,
                                    g, hist_full, hist_mask, inst_hist, meta,
                                    use_meta ? 1 : 0);

  k_argmax<<<N_INST, 256, 0, stream>>>(inst_hist, hist_full, hist_mask,
                                       inst_batch_ids, inst_seg, flags);

  dim3 mgrid(40, N_INST);
  if (use_meta) {
    k_mask<true><<<mgrid, 256, 0, stream>>>(mask_logits, meta, object_idxs, instance_labels,
                                            semantic_labels, batch_ids, flags,
                                            i_inter, i_up, i_ug, i_wbs, i_sn);
  } else {
    k_mask<false><<<mgrid, 256, 0, stream>>>(mask_logits, meta, object_idxs, instance_labels,
                                             semantic_labels, batch_ids, flags,
                                             i_inter, i_up, i_ug, i_wbs, i_sn);
  }
  k_final<<<1, 64, 0, stream>>>(g, i_inter, i_up, i_ug, i_wbs, i_sn, flags, epoch, out);
}